// Round 8
// baseline (343.480 us; speedup 1.0000x reference)
//
#include <hip/hip_runtime.h>
#include <cstdint>
#include <cstddef>

// Problem constants
#define BB 2
#define TT 2048
#define DMODEL 1024
#define NHEADS 16
#define DK 64

typedef short short8 __attribute__((ext_vector_type(8)));
typedef unsigned short ushort8 __attribute__((ext_vector_type(8)));
typedef float floatx4 __attribute__((ext_vector_type(4)));
typedef _Float16 half4 __attribute__((ext_vector_type(4)));

// gfx950 f16 MFMA 16x16x16: A/B = 4xf16 (2 VGPR), C/D = 4xf32
#define MFMA_PV(A, B, C) __builtin_amdgcn_mfma_f32_16x16x16f16(A, B, C, 0, 0, 0)

// ---------- helpers ----------
__device__ __forceinline__ unsigned short f2bf(float f) {
    uint32_t u = __builtin_bit_cast(uint32_t, f);
    uint32_t r = (u + 0x7FFFu + ((u >> 16) & 1u)) >> 16;
    return (unsigned short)r;
}

#define GLDS16(g, l) __builtin_amdgcn_global_load_lds( \
    (const __attribute__((address_space(1))) void*)(g), \
    (__attribute__((address_space(3))) void*)(l), 16, 0, 0)

// ---------- merged cast fp32 -> bf16 for x, w_qkv, w_out (one launch) ----------
__global__ void castk3(const float* __restrict__ x, unsigned short* __restrict__ xb,
                       const float* __restrict__ wq, unsigned short* __restrict__ wqb,
                       const float* __restrict__ wo, unsigned short* __restrict__ wob) {
    int bid = blockIdx.x;
    const float* in;
    unsigned short* out;
    int base;
    if (bid < 4096)       { in = x;  out = xb;  base = bid * 1024; }
    else if (bid < 7168)  { in = wq; out = wqb; base = (bid - 4096) * 1024; }
    else                  { in = wo; out = wob; base = (bid - 7168) * 1024; }
    int i = base + threadIdx.x * 4;
    float4 v = *(const float4*)(in + i);
    ushort4 o;
    o.x = f2bf(v.x); o.y = f2bf(v.y); o.z = f2bf(v.z); o.w = f2bf(v.w);
    *(ushort4*)(out + i) = o;
}

// ---------- bf16 MFMA GEMM, C = A * B^T  (A: [M][K], B: [N][K], C fp32 [M][N]) ----------
// XOR-swizzled LDS staging: row chunk cc stored at slot cc ^ ((row>>1)&3).
__global__ __launch_bounds__(256)
void gemm_bt(const unsigned short* __restrict__ A, const unsigned short* __restrict__ B,
             float* __restrict__ C, int M, int N, int K) {
    __shared__ unsigned short As[128 * 32];
    __shared__ unsigned short Bs[128 * 32];

    const int tid  = threadIdx.x;
    const int lane = tid & 63;
    const int w    = tid >> 6;
    const int wm   = w & 1;
    const int wn   = w >> 1;
    const int quad = lane >> 4;
    const int l16  = lane & 15;

    const int m0 = blockIdx.y * 128;
    const int n0 = blockIdx.x * 128;

    floatx4 acc[4][4];
#pragma unroll
    for (int a = 0; a < 4; a++)
#pragma unroll
        for (int b = 0; b < 4; b++)
            acc[a][b] = (floatx4){0.f, 0.f, 0.f, 0.f};

    const int c0 = w * 128 + lane;
    const int c1 = c0 + 64;
    const int r0 = c0 >> 2, cc0 = (c0 & 3) ^ ((r0 >> 1) & 3);
    const int r1 = c1 >> 2, cc1 = (c1 & 3) ^ ((r1 >> 1) & 3);

    const unsigned short* gA0 = A + (size_t)(m0 + r0) * K + cc0 * 8;
    const unsigned short* gA1 = A + (size_t)(m0 + r1) * K + cc1 * 8;
    const unsigned short* gB0 = B + (size_t)(n0 + r0) * K + cc0 * 8;
    const unsigned short* gB1 = B + (size_t)(n0 + r1) * K + cc1 * 8;

    unsigned short* lA0 = &As[(2 * w + 0) * 512];
    unsigned short* lA1 = &As[(2 * w + 1) * 512];
    unsigned short* lB0 = &Bs[(2 * w + 0) * 512];
    unsigned short* lB1 = &Bs[(2 * w + 1) * 512];

    const int rsw = (l16 >> 1) & 3;

    for (int k0 = 0; k0 < K; k0 += 32) {
        __syncthreads();
        GLDS16(gA0 + k0, lA0);
        GLDS16(gA1 + k0, lA1);
        GLDS16(gB0 + k0, lB0);
        GLDS16(gB1 + k0, lB1);
        __syncthreads();

        short8 af[4], bf[4];
#pragma unroll
        for (int t = 0; t < 4; t++) {
            af[t] = *(const short8*)&As[(wm * 64 + t * 16 + l16) * 32 + (quad ^ rsw) * 8];
            bf[t] = *(const short8*)&Bs[(wn * 64 + t * 16 + l16) * 32 + (quad ^ rsw) * 8];
        }
#pragma unroll
        for (int tm = 0; tm < 4; tm++)
#pragma unroll
            for (int tn = 0; tn < 4; tn++)
                acc[tm][tn] = __builtin_amdgcn_mfma_f32_16x16x32_bf16(
                    af[tm], bf[tn], acc[tm][tn], 0, 0, 0);
    }

#pragma unroll
    for (int tm = 0; tm < 4; tm++) {
#pragma unroll
        for (int tn = 0; tn < 4; tn++) {
#pragma unroll
            for (int r = 0; r < 4; r++) {
                int m = m0 + wm * 64 + tm * 16 + quad * 4 + r;
                int n = n0 + wn * 64 + tn * 16 + l16;
                C[(size_t)m * N + n] = acc[tm][tn][r];
            }
        }
    }
}

// ---------- RoPE + split: qkv fp32 [B*T][3072] -> qb,kb bf16 [B*H][T][64] ----------
// q is pre-scaled by 0.125*log2(e) so attention softmax runs in exp2 domain.
__global__ void rope_split(const float* __restrict__ qkv,
                           unsigned short* __restrict__ qb, unsigned short* __restrict__ kb) {
    int idx = blockIdx.x * blockDim.x + threadIdx.x;
    int p = idx & 31;
    int h = (idx >> 5) & 15;
    int t = (idx >> 9) & 2047;
    int b = idx >> 20;

    size_t src = (size_t)(b * TT + t) * 3072 + h * 64 + 2 * p;
    float2 q = *(const float2*)(qkv + src);
    float2 k = *(const float2*)(qkv + src + 1024);

    float invf = __powf(10000.f, -((float)(2 * p)) / 64.f);
    float ang  = (float)t * invf;
    float sn, cs;
    __sincosf(ang, &sn, &cs);

    const float QS = 0.18033688f;   // 0.125 * log2(e)
    size_t dst = ((size_t)(b * NHEADS + h) * TT + t) * 64 + 2 * p;
    ushort2 qo, ko;
    qo.x = f2bf((q.x * cs - q.y * sn) * QS); qo.y = f2bf((q.y * cs + q.x * sn) * QS);
    ko.x = f2bf(k.x * cs - k.y * sn); ko.y = f2bf(k.y * cs + k.x * sn);
    *(ushort2*)(qb + dst) = qo;
    *(ushort2*)(kb + dst) = ko;
}

// ---------- V transpose: qkv fp32 v-slice -> vtb f16 [B*H][64][T] ----------
__global__ __launch_bounds__(256)
void vtrans(const float* __restrict__ qkv, unsigned short* __restrict__ vtb) {
    __shared__ float tile[64][65];
    const int tid = threadIdx.x;
    const int bh = blockIdx.y;
    const int b = bh >> 4, h = bh & 15;
    const int t0 = blockIdx.x * 64;

    const int row = tid >> 2;
    const float* src = qkv + ((size_t)(b * TT) + t0 + row) * 3072 + 2048 + h * 64;
#pragma unroll
    for (int i = 0; i < 4; i++) {
        int c4 = (tid & 3) * 4 + i;   // 0..15
        float4 v = *(const float4*)(src + c4 * 4);
        tile[row][c4 * 4 + 0] = v.x;
        tile[row][c4 * 4 + 1] = v.y;
        tile[row][c4 * 4 + 2] = v.z;
        tile[row][c4 * 4 + 3] = v.w;
    }
    __syncthreads();

    const int d  = tid >> 2;
    const int tc = tid & 3;
    ushort8 o0, o1;
#pragma unroll
    for (int i = 0; i < 8; i++) {
        _Float16 hv = (_Float16)tile[tc * 16 + i][d];
        o0[i] = __builtin_bit_cast(unsigned short, hv);
    }
#pragma unroll
    for (int i = 0; i < 8; i++) {
        _Float16 hv = (_Float16)tile[tc * 16 + 8 + i][d];
        o1[i] = __builtin_bit_cast(unsigned short, hv);
    }
    unsigned short* dst = vtb + ((size_t)bh * 64 + d) * TT + t0 + tc * 16;
    *(ushort8*)(dst) = o0;
    *(ushort8*)(dst + 8) = o1;
}

// ---------- MFMA flash attention (causal), transposed-S form ----------
// One wave per block, 16 q-rows per wave. S^T = K·Q^T so that:
//  - softmax state (m,l,alpha) is a per-lane scalar (q = l16): 2 shfls per reduce
//  - P^T's C-layout IS the B-operand layout of 16x16x16 MFMA -> in-register f16
//    pack, no LDS anywhere in the kernel.
// K/V read directly from global (L2-resident; bh on blockIdx.x -> fixed XCD).
__global__ __launch_bounds__(64, 3)
void attn_mfma(const unsigned short* __restrict__ qb,
               const unsigned short* __restrict__ kb,
               const unsigned short* __restrict__ vtb,
               unsigned short* __restrict__ out) {
    const int lane = threadIdx.x & 63;
    const int quad = lane >> 4;
    const int l16  = lane & 15;

    const int bh    = blockIdx.x;                    // 32 % 8: head pinned to one XCD
    const int qc    = gridDim.y - 1 - blockIdx.y;    // longest first
    const int qbase = qc * 16;

    const unsigned short* Qp = qb + ((size_t)bh * TT + qbase) * 64;
    const unsigned short* Kp = kb + (size_t)bh * TT * 64;
    const _Float16*       Vp = (const _Float16*)vtb + (size_t)bh * 64 * TT;

    // Q as B-operand of 16x16x32: n = l16 = q-row, k = ks*32 + quad*8 + j
    short8 aq[2];
#pragma unroll
    for (int ks = 0; ks < 2; ks++)
        aq[ks] = *(const short8*)(Qp + (size_t)l16 * 64 + ks * 32 + quad * 8);

    floatx4 Oacc[4];   // O^T tiles: row d = dt*16 + quad*4 + r, col q = l16
#pragma unroll
    for (int dt = 0; dt < 4; dt++) Oacc[dt] = (floatx4){0.f, 0.f, 0.f, 0.f};
    float m = -1e30f, l = 0.f;

    const int ntiles = qc / 4 + 1;
    for (int it = 0; it < ntiles; ++it) {
        const int j0 = it * 64;

        // K fragments (A-operand: m = t = nt*16 + l16, k = ks*32 + quad*8 + j)
        short8 kf[2][4];
#pragma unroll
        for (int ks = 0; ks < 2; ks++)
#pragma unroll
            for (int nt = 0; nt < 4; nt++)
                kf[ks][nt] = *(const short8*)(Kp + (size_t)(j0 + nt * 16 + l16) * 64 + ks * 32 + quad * 8);

        // V^T fragments f16 (A-operand 16x16x16: m = d = dt*16 + l16, k = t = nt*16 + quad*4 + j)
        half4 vf[4][4];
#pragma unroll
        for (int dt = 0; dt < 4; dt++)
#pragma unroll
            for (int nt = 0; nt < 4; nt++)
                vf[dt][nt] = *(const half4*)(Vp + (size_t)(dt * 16 + l16) * TT + j0 + nt * 16 + quad * 4);

        // S^T = K Q^T: D[m=t][n=q], 4 row-tiles nt
        floatx4 sacc[4];
#pragma unroll
        for (int nt = 0; nt < 4; nt++) sacc[nt] = (floatx4){0.f, 0.f, 0.f, 0.f};
#pragma unroll
        for (int ks = 0; ks < 2; ks++)
#pragma unroll
            for (int nt = 0; nt < 4; nt++)
                sacc[nt] = __builtin_amdgcn_mfma_f32_16x16x32_bf16(kf[ks][nt], aq[ks], sacc[nt], 0, 0, 0);

        // causal mask (last tile only): t = j0 + nt*16 + quad*4 + r > q = qbase + l16
        if (it == ntiles - 1) {
            const int qg = qbase + l16;
#pragma unroll
            for (int nt = 0; nt < 4; nt++)
#pragma unroll
                for (int r = 0; r < 4; r++)
                    if (j0 + nt * 16 + quad * 4 + r > qg) sacc[nt][r] = -1e30f;
        }

        // online softmax, per-lane scalar state (q = l16), exp2 domain
        float mx = sacc[0][0];
#pragma unroll
        for (int nt = 0; nt < 4; nt++)
#pragma unroll
            for (int r = 0; r < 4; r++) mx = fmaxf(mx, sacc[nt][r]);
        mx = fmaxf(mx, __shfl_xor(mx, 16));
        mx = fmaxf(mx, __shfl_xor(mx, 32));
        float mnew  = fmaxf(m, mx);
        float alpha = __builtin_amdgcn_exp2f(m - mnew);
        m = mnew;
        float psum = 0.f;
#pragma unroll
        for (int nt = 0; nt < 4; nt++)
#pragma unroll
            for (int r = 0; r < 4; r++) {
                float p = __builtin_amdgcn_exp2f(sacc[nt][r] - mnew);
                sacc[nt][r] = p;
                psum += p;
            }
        psum += __shfl_xor(psum, 16);
        psum += __shfl_xor(psum, 32);
        l = l * alpha + psum;

#pragma unroll
        for (int dt = 0; dt < 4; dt++)
#pragma unroll
            for (int r = 0; r < 4; r++) Oacc[dt][r] *= alpha;

        // P^T pack: C-layout == B-operand layout of 16x16x16 (k=quad*4+j, n=l16)
        half4 bp[4];
#pragma unroll
        for (int nt = 0; nt < 4; nt++) {
            half4 h;
            h[0] = (_Float16)sacc[nt][0];
            h[1] = (_Float16)sacc[nt][1];
            h[2] = (_Float16)sacc[nt][2];
            h[3] = (_Float16)sacc[nt][3];
            bp[nt] = h;
        }

        // O^T += V^T · P^T
#pragma unroll
        for (int dt = 0; dt < 4; dt++)
#pragma unroll
            for (int nt = 0; nt < 4; nt++)
                Oacc[dt] = MFMA_PV(vf[dt][nt], bp[nt], Oacc[dt]);
    }

    // epilogue: out[b][t=qbase+l16][h*64 + dt*16 + quad*4 + r] bf16
    const int b = bh >> 4, h = bh & 15;
    const float inv = 1.f / l;
    const size_t base = ((size_t)(b * TT + qbase + l16)) * DMODEL + h * 64 + quad * 4;
#pragma unroll
    for (int dt = 0; dt < 4; dt++) {
        ushort4 pk;
        pk.x = f2bf(Oacc[dt][0] * inv);
        pk.y = f2bf(Oacc[dt][1] * inv);
        pk.z = f2bf(Oacc[dt][2] * inv);
        pk.w = f2bf(Oacc[dt][3] * inv);
        *(ushort4*)(out + base + dt * 16) = pk;
    }
}

// ---------- launch ----------
extern "C" void kernel_launch(void* const* d_in, const int* in_sizes, int n_in,
                              void* d_out, int out_size, void* d_ws, size_t ws_size,
                              hipStream_t stream) {
    const float* x     = (const float*)d_in[0];   // [2,2048,1024]
    const float* w_qkv = (const float*)d_in[1];   // [3072,1024]
    const float* w_out = (const float*)d_in[2];   // [1024,1024]
    float* out = (float*)d_out;                   // [2,2048,1024]

    char* ws = (char*)d_ws;

    unsigned short* xb   = (unsigned short*)(ws);                 // 8 MB
    unsigned short* wqb  = (unsigned short*)(ws + 8388608);       // 6 MB
    unsigned short* wob  = (unsigned short*)(ws + 14680064);      // 2 MB
    float*          qkv  = (float*)(ws + 16777216);               // 48 MB
    unsigned short* qb   = (unsigned short*)(ws + 67108864);      // 8 MB
    unsigned short* kb   = (unsigned short*)(ws + 75497472);      // 8 MB
    unsigned short* vtb  = (unsigned short*)(ws + 83886080);      // 8 MB (f16)
    unsigned short* attb = (unsigned short*)(ws + 92274688);      // 8 MB

    castk3<<<8192, 256, 0, stream>>>(x, xb, w_qkv, wqb, w_out, wob);

    // qkv = x @ w_qkv^T   (M=4096, N=3072, K=1024)
    gemm_bt<<<dim3(3072 / 128, 4096 / 128), 256, 0, stream>>>(xb, wqb, qkv, 4096, 3072, 1024);

    rope_split<<<(BB * TT * NHEADS * 32) / 256, 256, 0, stream>>>(qkv, qb, kb);
    vtrans<<<dim3(TT / 64, BB * NHEADS), 256, 0, stream>>>(qkv, vtb);

    // grid: x = bh (XCD locality), y = q-chunk of 16 rows (reversed inside kernel)
    attn_mfma<<<dim3(BB * NHEADS, TT / 16), 64, 0, stream>>>(qb, kb, vtb, attb);

    // out = attn @ w_out^T (M=4096, N=1024, K=1024)
    gemm_bt<<<dim3(1024 / 128, 4096 / 128), 256, 0, stream>>>(attb, wob, out, 4096, 1024, 1024);
}

// Round 9
// 211.036 us; speedup vs baseline: 1.6276x; 1.6276x over previous
//
#include <hip/hip_runtime.h>
#include <cstdint>
#include <cstddef>

// Problem constants
#define BB 2
#define TT 2048
#define DMODEL 1024
#define NHEADS 16
#define DK 64

typedef short short8 __attribute__((ext_vector_type(8)));
typedef unsigned short ushort8 __attribute__((ext_vector_type(8)));
typedef float floatx4 __attribute__((ext_vector_type(4)));
typedef _Float16 half4 __attribute__((ext_vector_type(4)));

// gfx950 f16 MFMA 16x16x16: A/B = 4xf16 (2 VGPR), C/D = 4xf32
#define MFMA_PV(A, B, C) __builtin_amdgcn_mfma_f32_16x16x16f16(A, B, C, 0, 0, 0)

// ---------- helpers ----------
__device__ __forceinline__ unsigned short f2bf(float f) {
    uint32_t u = __builtin_bit_cast(uint32_t, f);
    uint32_t r = (u + 0x7FFFu + ((u >> 16) & 1u)) >> 16;
    return (unsigned short)r;
}

#define GLDS16(g, l) __builtin_amdgcn_global_load_lds( \
    (const __attribute__((address_space(1))) void*)(g), \
    (__attribute__((address_space(3))) void*)(l), 16, 0, 0)

// ---------- merged cast fp32 -> bf16 for x, w_qkv, w_out (one launch) ----------
__global__ void castk3(const float* __restrict__ x, unsigned short* __restrict__ xb,
                       const float* __restrict__ wq, unsigned short* __restrict__ wqb,
                       const float* __restrict__ wo, unsigned short* __restrict__ wob) {
    int bid = blockIdx.x;
    const float* in;
    unsigned short* out;
    int base;
    if (bid < 4096)       { in = x;  out = xb;  base = bid * 1024; }
    else if (bid < 7168)  { in = wq; out = wqb; base = (bid - 4096) * 1024; }
    else                  { in = wo; out = wob; base = (bid - 7168) * 1024; }
    int i = base + threadIdx.x * 4;
    float4 v = *(const float4*)(in + i);
    ushort4 o;
    o.x = f2bf(v.x); o.y = f2bf(v.y); o.z = f2bf(v.z); o.w = f2bf(v.w);
    *(ushort4*)(out + i) = o;
}

// ---------- bf16 MFMA GEMM, C = A * B^T  (A: [M][K], B: [N][K], C fp32 [M][N]) ----------
__global__ __launch_bounds__(256)
void gemm_bt(const unsigned short* __restrict__ A, const unsigned short* __restrict__ B,
             float* __restrict__ C, int M, int N, int K) {
    __shared__ unsigned short As[128 * 32];
    __shared__ unsigned short Bs[128 * 32];

    const int tid  = threadIdx.x;
    const int lane = tid & 63;
    const int w    = tid >> 6;
    const int wm   = w & 1;
    const int wn   = w >> 1;
    const int quad = lane >> 4;
    const int l16  = lane & 15;

    const int m0 = blockIdx.y * 128;
    const int n0 = blockIdx.x * 128;

    floatx4 acc[4][4];
#pragma unroll
    for (int a = 0; a < 4; a++)
#pragma unroll
        for (int b = 0; b < 4; b++)
            acc[a][b] = (floatx4){0.f, 0.f, 0.f, 0.f};

    const int c0 = w * 128 + lane;
    const int c1 = c0 + 64;
    const int r0 = c0 >> 2, cc0 = (c0 & 3) ^ ((r0 >> 1) & 3);
    const int r1 = c1 >> 2, cc1 = (c1 & 3) ^ ((r1 >> 1) & 3);

    const unsigned short* gA0 = A + (size_t)(m0 + r0) * K + cc0 * 8;
    const unsigned short* gA1 = A + (size_t)(m0 + r1) * K + cc1 * 8;
    const unsigned short* gB0 = B + (size_t)(n0 + r0) * K + cc0 * 8;
    const unsigned short* gB1 = B + (size_t)(n0 + r1) * K + cc1 * 8;

    unsigned short* lA0 = &As[(2 * w + 0) * 512];
    unsigned short* lA1 = &As[(2 * w + 1) * 512];
    unsigned short* lB0 = &Bs[(2 * w + 0) * 512];
    unsigned short* lB1 = &Bs[(2 * w + 1) * 512];

    const int rsw = (l16 >> 1) & 3;

    for (int k0 = 0; k0 < K; k0 += 32) {
        __syncthreads();
        GLDS16(gA0 + k0, lA0);
        GLDS16(gA1 + k0, lA1);
        GLDS16(gB0 + k0, lB0);
        GLDS16(gB1 + k0, lB1);
        __syncthreads();

        short8 af[4], bf[4];
#pragma unroll
        for (int t = 0; t < 4; t++) {
            af[t] = *(const short8*)&As[(wm * 64 + t * 16 + l16) * 32 + (quad ^ rsw) * 8];
            bf[t] = *(const short8*)&Bs[(wn * 64 + t * 16 + l16) * 32 + (quad ^ rsw) * 8];
        }
#pragma unroll
        for (int tm = 0; tm < 4; tm++)
#pragma unroll
            for (int tn = 0; tn < 4; tn++)
                acc[tm][tn] = __builtin_amdgcn_mfma_f32_16x16x32_bf16(
                    af[tm], bf[tn], acc[tm][tn], 0, 0, 0);
    }

#pragma unroll
    for (int tm = 0; tm < 4; tm++) {
#pragma unroll
        for (int tn = 0; tn < 4; tn++) {
#pragma unroll
            for (int r = 0; r < 4; r++) {
                int m = m0 + wm * 64 + tm * 16 + quad * 4 + r;
                int n = n0 + wn * 64 + tn * 16 + l16;
                C[(size_t)m * N + n] = acc[tm][tn][r];
            }
        }
    }
}

// ---------- RoPE + split: qkv fp32 [B*T][3072] -> qb,kb bf16 [B*H][T][64] ----------
// q pre-scaled by 0.125*log2(e): softmax runs in exp2 domain.
__global__ void rope_split(const float* __restrict__ qkv,
                           unsigned short* __restrict__ qb, unsigned short* __restrict__ kb) {
    int idx = blockIdx.x * blockDim.x + threadIdx.x;
    int p = idx & 31;
    int h = (idx >> 5) & 15;
    int t = (idx >> 9) & 2047;
    int b = idx >> 20;

    size_t src = (size_t)(b * TT + t) * 3072 + h * 64 + 2 * p;
    float2 q = *(const float2*)(qkv + src);
    float2 k = *(const float2*)(qkv + src + 1024);

    float invf = __powf(10000.f, -((float)(2 * p)) / 64.f);
    float ang  = (float)t * invf;
    float sn, cs;
    __sincosf(ang, &sn, &cs);

    const float QS = 0.18033688f;   // 0.125 * log2(e)
    size_t dst = ((size_t)(b * NHEADS + h) * TT + t) * 64 + 2 * p;
    ushort2 qo, ko;
    qo.x = f2bf((q.x * cs - q.y * sn) * QS); qo.y = f2bf((q.y * cs + q.x * sn) * QS);
    ko.x = f2bf(k.x * cs - k.y * sn); ko.y = f2bf(k.y * cs + k.x * sn);
    *(ushort2*)(qb + dst) = qo;
    *(ushort2*)(kb + dst) = ko;
}

// ---------- V transpose: qkv fp32 v-slice -> vtb f16 [B*H][64][T] ----------
__global__ __launch_bounds__(256)
void vtrans(const float* __restrict__ qkv, unsigned short* __restrict__ vtb) {
    __shared__ float tile[64][65];
    const int tid = threadIdx.x;
    const int bh = blockIdx.y;
    const int b = bh >> 4, h = bh & 15;
    const int t0 = blockIdx.x * 64;

    const int row = tid >> 2;
    const float* src = qkv + ((size_t)(b * TT) + t0 + row) * 3072 + 2048 + h * 64;
#pragma unroll
    for (int i = 0; i < 4; i++) {
        int c4 = (tid & 3) * 4 + i;   // 0..15
        float4 v = *(const float4*)(src + c4 * 4);
        tile[row][c4 * 4 + 0] = v.x;
        tile[row][c4 * 4 + 1] = v.y;
        tile[row][c4 * 4 + 2] = v.z;
        tile[row][c4 * 4 + 3] = v.w;
    }
    __syncthreads();

    const int d  = tid >> 2;
    const int tc = tid & 3;
    ushort8 o0, o1;
#pragma unroll
    for (int i = 0; i < 8; i++) {
        _Float16 hv = (_Float16)tile[tc * 16 + i][d];
        o0[i] = __builtin_bit_cast(unsigned short, hv);
    }
#pragma unroll
    for (int i = 0; i < 8; i++) {
        _Float16 hv = (_Float16)tile[tc * 16 + 8 + i][d];
        o1[i] = __builtin_bit_cast(unsigned short, hv);
    }
    unsigned short* dst = vtb + ((size_t)bh * 64 + d) * TT + t0 + tc * 16;
    *(ushort8*)(dst) = o0;
    *(ushort8*)(dst + 8) = o1;
}

// ---------- MFMA flash attention (causal): transposed-S + double-buffered LDS ----------
// Block = 4 waves, 64 q-rows (wave w owns rows q0+w*16..+15). KV tiles of 64 staged
// into LDS via global_load_lds (fire-and-forget), double-buffered: stage(i+1) issued
// before compute(i); single __syncthreads per iteration drains it after compute.
// S^T = K·Q^T form: per-lane scalar softmax (2 shfls), in-register P f16 pack, no
// LDS for P. K staging swizzled (16B chunk ^ row&7); V^T swizzled (16B chunk ^ (d>>1)&7).
__global__ __launch_bounds__(256, 4)
void attn_mfma(const unsigned short* __restrict__ qb,
               const unsigned short* __restrict__ kb,
               const unsigned short* __restrict__ vtb,
               unsigned short* __restrict__ out) {
    __shared__ unsigned short Ks[2][64 * 64];   // [t][d] bf16, chunk-swizzled
    __shared__ unsigned short Vs[2][64 * 64];   // [d][t] f16,  chunk-swizzled

    const int tid  = threadIdx.x;
    const int lane = tid & 63;
    const int w    = tid >> 6;
    const int quad = lane >> 4;
    const int l16  = lane & 15;

    const int bh    = blockIdx.x;     // head pinned to one XCD (32 blocks % 8)
    const int qtile = blockIdx.y;     // y-major dispatch interleaves lengths across CUs
    const int q0    = qtile * 64;

    const unsigned short* Qp = qb + ((size_t)bh * TT + q0 + w * 16) * 64;
    const unsigned short* Kp = kb + (size_t)bh * TT * 64;
    const unsigned short* Vp = vtb + (size_t)bh * 64 * TT;   // f16 bits in ushort

    // Q as B-operand of 16x16x32: n = l16 = q-row (wave-local), k = ks*32+quad*8+j
    short8 aq[2];
#pragma unroll
    for (int ks = 0; ks < 2; ks++)
        aq[ks] = *(const short8*)(Qp + (size_t)l16 * 64 + ks * 32 + quad * 8);

    floatx4 Oacc[4];   // O^T: row d = dt*16 + quad*4 + r, col q = l16
#pragma unroll
    for (int dt = 0; dt < 4; dt++) Oacc[dt] = (floatx4){0.f, 0.f, 0.f, 0.f};
    float m = -1e30f, l = 0.f;

    const int ntiles = qtile + 1;

    // stage tile IT into buffer P: 512 K-chunks + 512 V-chunks of 16B, 2+2 per thread
#define STAGE(IT, P)                                                                      \
    {                                                                                     \
        const int j0s = (IT) * 64;                                                        \
        _Pragma("unroll")                                                                 \
        for (int rep = 0; rep < 2; rep++) {                                               \
            int c    = rep * 256 + tid;                                                   \
            int row  = c >> 3, sl = c & 7;                                                \
            GLDS16(Kp + (size_t)(j0s + row) * 64 + (sl ^ (row & 7)) * 8, &Ks[P][c * 8]);  \
            GLDS16(Vp + (size_t)row * TT + j0s + (sl ^ ((row >> 1) & 7)) * 8,             \
                   &Vs[P][c * 8]);                                                        \
        }                                                                                 \
    }

    STAGE(0, 0);
    __syncthreads();

    const int ksw = l16 & 7;          // K fragment slot swizzle
    const int vsw = (l16 >> 1) & 7;   // V fragment slot swizzle

    for (int it = 0; it < ntiles; ++it) {
        const int p = it & 1;
        if (it + 1 < ntiles) STAGE(it + 1, p ^ 1);

        // S^T = K Q^T: A = K rows (m = t = nt*16+l16), B = aq
        floatx4 sacc[4];
#pragma unroll
        for (int nt = 0; nt < 4; nt++) sacc[nt] = (floatx4){0.f, 0.f, 0.f, 0.f};
#pragma unroll
        for (int ks = 0; ks < 2; ks++)
#pragma unroll
            for (int nt = 0; nt < 4; nt++) {
                short8 kf = *(const short8*)&Ks[p][(nt * 16 + l16) * 64 + ((ks * 4 + quad) ^ ksw) * 8];
                sacc[nt] = __builtin_amdgcn_mfma_f32_16x16x32_bf16(kf, aq[ks], sacc[nt], 0, 0, 0);
            }

        // causal mask (diagonal tile only): t = it*64 + nt*16 + quad*4 + r, q = q0 + w*16 + l16
        if (it == qtile) {
            const int qg = w * 16 + l16;   // t-local threshold within this tile
#pragma unroll
            for (int nt = 0; nt < 4; nt++)
#pragma unroll
                for (int r = 0; r < 4; r++)
                    if (nt * 16 + quad * 4 + r > qg) sacc[nt][r] = -1e30f;
        }

        // online softmax, per-lane scalar state (q = l16), exp2 domain
        float mx = sacc[0][0];
#pragma unroll
        for (int nt = 0; nt < 4; nt++)
#pragma unroll
            for (int r = 0; r < 4; r++) mx = fmaxf(mx, sacc[nt][r]);
        mx = fmaxf(mx, __shfl_xor(mx, 16));
        mx = fmaxf(mx, __shfl_xor(mx, 32));
        float mnew  = fmaxf(m, mx);
        float alpha = __builtin_amdgcn_exp2f(m - mnew);
        m = mnew;
        float psum = 0.f;
#pragma unroll
        for (int nt = 0; nt < 4; nt++)
#pragma unroll
            for (int r = 0; r < 4; r++) {
                float pv = __builtin_amdgcn_exp2f(sacc[nt][r] - mnew);
                sacc[nt][r] = pv;
                psum += pv;
            }
        psum += __shfl_xor(psum, 16);
        psum += __shfl_xor(psum, 32);
        l = l * alpha + psum;

#pragma unroll
        for (int dt = 0; dt < 4; dt++)
#pragma unroll
            for (int r = 0; r < 4; r++) Oacc[dt][r] *= alpha;

        // P^T pack: C-layout == B-operand of 16x16x16 f16 (k = quad*4+j, n = l16)
        half4 bp[4];
#pragma unroll
        for (int nt = 0; nt < 4; nt++) {
            half4 h;
            h[0] = (_Float16)sacc[nt][0];
            h[1] = (_Float16)sacc[nt][1];
            h[2] = (_Float16)sacc[nt][2];
            h[3] = (_Float16)sacc[nt][3];
            bp[nt] = h;
        }

        // O^T += V^T · P^T   (A = V^T: m = d = dt*16+l16, k = nt*16 + quad*4 + j)
#pragma unroll
        for (int dt = 0; dt < 4; dt++)
#pragma unroll
            for (int nt = 0; nt < 4; nt++) {
                int c = nt * 2 + (quad >> 1);           // 16B chunk of the 8B we need
                half4 vf = *(const half4*)&Vs[p][(dt * 16 + l16) * 64 + (c ^ vsw) * 8 + (quad & 1) * 4];
                Oacc[dt] = MFMA_PV(vf, bp[nt], Oacc[dt]);
            }

        __syncthreads();   // drains stage(it+1); protects buffers for next iteration
    }
#undef STAGE

    // epilogue: out[b][t = q0 + w*16 + l16][h*64 + dt*16 + quad*4 + r] bf16
    const int b = bh >> 4, h = bh & 15;
    const float inv = 1.f / l;
    const size_t base = ((size_t)(b * TT + q0 + w * 16 + l16)) * DMODEL + h * 64 + quad * 4;
#pragma unroll
    for (int dt = 0; dt < 4; dt++) {
        ushort4 pk;
        pk.x = f2bf(Oacc[dt][0] * inv);
        pk.y = f2bf(Oacc[dt][1] * inv);
        pk.z = f2bf(Oacc[dt][2] * inv);
        pk.w = f2bf(Oacc[dt][3] * inv);
        *(ushort4*)(out + base + dt * 16) = pk;
    }
}

// ---------- launch ----------
extern "C" void kernel_launch(void* const* d_in, const int* in_sizes, int n_in,
                              void* d_out, int out_size, void* d_ws, size_t ws_size,
                              hipStream_t stream) {
    const float* x     = (const float*)d_in[0];   // [2,2048,1024]
    const float* w_qkv = (const float*)d_in[1];   // [3072,1024]
    const float* w_out = (const float*)d_in[2];   // [1024,1024]
    float* out = (float*)d_out;                   // [2,2048,1024]

    char* ws = (char*)d_ws;

    unsigned short* xb   = (unsigned short*)(ws);                 // 8 MB
    unsigned short* wqb  = (unsigned short*)(ws + 8388608);       // 6 MB
    unsigned short* wob  = (unsigned short*)(ws + 14680064);      // 2 MB
    float*          qkv  = (float*)(ws + 16777216);               // 48 MB
    unsigned short* qb   = (unsigned short*)(ws + 67108864);      // 8 MB
    unsigned short* kb   = (unsigned short*)(ws + 75497472);      // 8 MB
    unsigned short* vtb  = (unsigned short*)(ws + 83886080);      // 8 MB (f16)
    unsigned short* attb = (unsigned short*)(ws + 92274688);      // 8 MB

    castk3<<<8192, 256, 0, stream>>>(x, xb, w_qkv, wqb, w_out, wob);

    // qkv = x @ w_qkv^T   (M=4096, N=3072, K=1024)
    gemm_bt<<<dim3(3072 / 128, 4096 / 128), 256, 0, stream>>>(xb, wqb, qkv, 4096, 3072, 1024);

    rope_split<<<(BB * TT * NHEADS * 32) / 256, 256, 0, stream>>>(qkv, qb, kb);
    vtrans<<<dim3(TT / 64, BB * NHEADS), 256, 0, stream>>>(qkv, vtb);

    // grid: x = bh (XCD locality), y = qtile (y-major dispatch mixes lengths per CU)
    attn_mfma<<<dim3(BB * NHEADS, TT / 64), 256, 0, stream>>>(qb, kb, vtb, attb);

    // out = attn @ w_out^T (M=4096, N=1024, K=1024)
    gemm_bt<<<dim3(1024 / 128, 4096 / 128), 256, 0, stream>>>(attb, wob, out, 4096, 1024, 1024);
}

// Round 10
// 201.264 us; speedup vs baseline: 1.7066x; 1.0486x over previous
//
#include <hip/hip_runtime.h>
#include <cstdint>
#include <cstddef>

// Problem constants
#define BB 2
#define TT 2048
#define DMODEL 1024
#define NHEADS 16
#define DK 64

typedef short short8 __attribute__((ext_vector_type(8)));
typedef unsigned short ushort8 __attribute__((ext_vector_type(8)));
typedef float floatx4 __attribute__((ext_vector_type(4)));
typedef _Float16 half4 __attribute__((ext_vector_type(4)));

// gfx950 f16 MFMA 16x16x16: A/B = 4xf16 (2 VGPR), C/D = 4xf32
#define MFMA_PV(A, B, C) __builtin_amdgcn_mfma_f32_16x16x16f16(A, B, C, 0, 0, 0)

// ---------- helpers ----------
__device__ __forceinline__ unsigned short f2bf(float f) {
    uint32_t u = __builtin_bit_cast(uint32_t, f);
    uint32_t r = (u + 0x7FFFu + ((u >> 16) & 1u)) >> 16;
    return (unsigned short)r;
}

#define GLDS16(g, l) __builtin_amdgcn_global_load_lds( \
    (const __attribute__((address_space(1))) void*)(g), \
    (__attribute__((address_space(3))) void*)(l), 16, 0, 0)

// ---------- merged cast fp32 -> bf16 for x, w_qkv, w_out (one launch) ----------
__global__ void castk3(const float* __restrict__ x, unsigned short* __restrict__ xb,
                       const float* __restrict__ wq, unsigned short* __restrict__ wqb,
                       const float* __restrict__ wo, unsigned short* __restrict__ wob) {
    int bid = blockIdx.x;
    const float* in;
    unsigned short* out;
    int base;
    if (bid < 4096)       { in = x;  out = xb;  base = bid * 1024; }
    else if (bid < 7168)  { in = wq; out = wqb; base = (bid - 4096) * 1024; }
    else                  { in = wo; out = wob; base = (bid - 7168) * 1024; }
    int i = base + threadIdx.x * 4;
    float4 v = *(const float4*)(in + i);
    ushort4 o;
    o.x = f2bf(v.x); o.y = f2bf(v.y); o.z = f2bf(v.z); o.w = f2bf(v.w);
    *(ushort4*)(out + i) = o;
}

// ---------- bf16 MFMA GEMM, C = A * B^T  (A: [M][K], B: [N][K], C fp32 [M][N]) ----------
__global__ __launch_bounds__(256)
void gemm_bt(const unsigned short* __restrict__ A, const unsigned short* __restrict__ B,
             float* __restrict__ C, int M, int N, int K) {
    __shared__ unsigned short As[128 * 32];
    __shared__ unsigned short Bs[128 * 32];

    const int tid  = threadIdx.x;
    const int lane = tid & 63;
    const int w    = tid >> 6;
    const int wm   = w & 1;
    const int wn   = w >> 1;
    const int quad = lane >> 4;
    const int l16  = lane & 15;

    const int m0 = blockIdx.y * 128;
    const int n0 = blockIdx.x * 128;

    floatx4 acc[4][4];
#pragma unroll
    for (int a = 0; a < 4; a++)
#pragma unroll
        for (int b = 0; b < 4; b++)
            acc[a][b] = (floatx4){0.f, 0.f, 0.f, 0.f};

    const int c0 = w * 128 + lane;
    const int c1 = c0 + 64;
    const int r0 = c0 >> 2, cc0 = (c0 & 3) ^ ((r0 >> 1) & 3);
    const int r1 = c1 >> 2, cc1 = (c1 & 3) ^ ((r1 >> 1) & 3);

    const unsigned short* gA0 = A + (size_t)(m0 + r0) * K + cc0 * 8;
    const unsigned short* gA1 = A + (size_t)(m0 + r1) * K + cc1 * 8;
    const unsigned short* gB0 = B + (size_t)(n0 + r0) * K + cc0 * 8;
    const unsigned short* gB1 = B + (size_t)(n0 + r1) * K + cc1 * 8;

    unsigned short* lA0 = &As[(2 * w + 0) * 512];
    unsigned short* lA1 = &As[(2 * w + 1) * 512];
    unsigned short* lB0 = &Bs[(2 * w + 0) * 512];
    unsigned short* lB1 = &Bs[(2 * w + 1) * 512];

    const int rsw = (l16 >> 1) & 3;

    for (int k0 = 0; k0 < K; k0 += 32) {
        __syncthreads();
        GLDS16(gA0 + k0, lA0);
        GLDS16(gA1 + k0, lA1);
        GLDS16(gB0 + k0, lB0);
        GLDS16(gB1 + k0, lB1);
        __syncthreads();

        short8 af[4], bf[4];
#pragma unroll
        for (int t = 0; t < 4; t++) {
            af[t] = *(const short8*)&As[(wm * 64 + t * 16 + l16) * 32 + (quad ^ rsw) * 8];
            bf[t] = *(const short8*)&Bs[(wn * 64 + t * 16 + l16) * 32 + (quad ^ rsw) * 8];
        }
#pragma unroll
        for (int tm = 0; tm < 4; tm++)
#pragma unroll
            for (int tn = 0; tn < 4; tn++)
                acc[tm][tn] = __builtin_amdgcn_mfma_f32_16x16x32_bf16(
                    af[tm], bf[tn], acc[tm][tn], 0, 0, 0);
    }

#pragma unroll
    for (int tm = 0; tm < 4; tm++) {
#pragma unroll
        for (int tn = 0; tn < 4; tn++) {
#pragma unroll
            for (int r = 0; r < 4; r++) {
                int m = m0 + wm * 64 + tm * 16 + quad * 4 + r;
                int n = n0 + wn * 64 + tn * 16 + l16;
                C[(size_t)m * N + n] = acc[tm][tn][r];
            }
        }
    }
}

// ---------- RoPE + split: qkv fp32 [B*T][3072] -> qb,kb bf16 [B*H][T][64] ----------
// q pre-scaled by 0.125*log2(e): softmax runs in exp2 domain.
__global__ void rope_split(const float* __restrict__ qkv,
                           unsigned short* __restrict__ qb, unsigned short* __restrict__ kb) {
    int idx = blockIdx.x * blockDim.x + threadIdx.x;
    int p = idx & 31;
    int h = (idx >> 5) & 15;
    int t = (idx >> 9) & 2047;
    int b = idx >> 20;

    size_t src = (size_t)(b * TT + t) * 3072 + h * 64 + 2 * p;
    float2 q = *(const float2*)(qkv + src);
    float2 k = *(const float2*)(qkv + src + 1024);

    float invf = __powf(10000.f, -((float)(2 * p)) / 64.f);
    float ang  = (float)t * invf;
    float sn, cs;
    __sincosf(ang, &sn, &cs);

    const float QS = 0.18033688f;   // 0.125 * log2(e)
    size_t dst = ((size_t)(b * NHEADS + h) * TT + t) * 64 + 2 * p;
    ushort2 qo, ko;
    qo.x = f2bf((q.x * cs - q.y * sn) * QS); qo.y = f2bf((q.y * cs + q.x * sn) * QS);
    ko.x = f2bf(k.x * cs - k.y * sn); ko.y = f2bf(k.y * cs + k.x * sn);
    *(ushort2*)(qb + dst) = qo;
    *(ushort2*)(kb + dst) = ko;
}

// ---------- V transpose: qkv fp32 v-slice -> vtb f16 [B*H][64][T] ----------
// Odd d rows store each 16B chunk with its two 8B halves swapped, so the attn
// kernel's b64 fragment reads cover all 16 LDS bank-pairs within each 16-lane
// phase (kills the 2x phase-local bank conflict).
__global__ __launch_bounds__(256)
void vtrans(const float* __restrict__ qkv, unsigned short* __restrict__ vtb) {
    __shared__ float tile[64][65];
    const int tid = threadIdx.x;
    const int bh = blockIdx.y;
    const int b = bh >> 4, h = bh & 15;
    const int t0 = blockIdx.x * 64;

    const int row = tid >> 2;
    const float* src = qkv + ((size_t)(b * TT) + t0 + row) * 3072 + 2048 + h * 64;
#pragma unroll
    for (int i = 0; i < 4; i++) {
        int c4 = (tid & 3) * 4 + i;   // 0..15
        float4 v = *(const float4*)(src + c4 * 4);
        tile[row][c4 * 4 + 0] = v.x;
        tile[row][c4 * 4 + 1] = v.y;
        tile[row][c4 * 4 + 2] = v.z;
        tile[row][c4 * 4 + 3] = v.w;
    }
    __syncthreads();

    const int d  = tid >> 2;
    const int tc = tid & 3;
    const int hs = (d & 1) * 4;       // half-swap for odd rows
    ushort8 o0, o1;
#pragma unroll
    for (int i = 0; i < 8; i++) {
        _Float16 hv = (_Float16)tile[tc * 16 + (i ^ hs)][d];
        o0[i] = __builtin_bit_cast(unsigned short, hv);
    }
#pragma unroll
    for (int i = 0; i < 8; i++) {
        _Float16 hv = (_Float16)tile[tc * 16 + 8 + (i ^ hs)][d];
        o1[i] = __builtin_bit_cast(unsigned short, hv);
    }
    unsigned short* dst = vtb + ((size_t)bh * 64 + d) * TT + t0 + tc * 16;
    *(ushort8*)(dst) = o0;
    *(ushort8*)(dst + 8) = o1;
}

// ---------- MFMA flash attention (causal): transposed-S + double-buffered LDS ----------
// Block = 4 waves, 64 q-rows. KV tiles staged via global_load_lds, double-buffered:
// stage(i+1) issued before compute(i); one __syncthreads per iteration.
// S^T = K·Q^T: per-lane scalar softmax (2 shfls), in-register P f16 pack.
// Longest qtile dispatched first (LPT packing). 5 blocks/CU (LDS = 5x32KB = 160KB).
__global__ __launch_bounds__(256, 5)
void attn_mfma(const unsigned short* __restrict__ qb,
               const unsigned short* __restrict__ kb,
               const unsigned short* __restrict__ vtb,
               unsigned short* __restrict__ out) {
    __shared__ unsigned short Ks[2][64 * 64];   // [t][d] bf16, chunk-swizzled
    __shared__ unsigned short Vs[2][64 * 64];   // [d][t] f16,  chunk-swizzled + half-swapped

    const int tid  = threadIdx.x;
    const int lane = tid & 63;
    const int w    = tid >> 6;
    const int quad = lane >> 4;
    const int l16  = lane & 15;

    const int bh    = blockIdx.x;                    // head pinned to one XCD (32 % 8)
    const int qtile = gridDim.y - 1 - blockIdx.y;    // longest first
    const int q0    = qtile * 64;

    const unsigned short* Qp = qb + ((size_t)bh * TT + q0 + w * 16) * 64;
    const unsigned short* Kp = kb + (size_t)bh * TT * 64;
    const unsigned short* Vp = vtb + (size_t)bh * 64 * TT;   // f16 bits in ushort

    // Q as B-operand of 16x16x32: n = l16 = q-row (wave-local), k = ks*32+quad*8+j
    short8 aq[2];
#pragma unroll
    for (int ks = 0; ks < 2; ks++)
        aq[ks] = *(const short8*)(Qp + (size_t)l16 * 64 + ks * 32 + quad * 8);

    floatx4 Oacc[4];   // O^T: row d = dt*16 + quad*4 + r, col q = l16
#pragma unroll
    for (int dt = 0; dt < 4; dt++) Oacc[dt] = (floatx4){0.f, 0.f, 0.f, 0.f};
    float m = -1e30f, l = 0.f;

    const int ntiles = qtile + 1;

    // stage tile IT into buffer P: 512 K-chunks + 512 V-chunks of 16B, 2+2 per thread
#define STAGE(IT, P)                                                                      \
    {                                                                                     \
        const int j0s = (IT) * 64;                                                        \
        _Pragma("unroll")                                                                 \
        for (int rep = 0; rep < 2; rep++) {                                               \
            int c    = rep * 256 + tid;                                                   \
            int row  = c >> 3, sl = c & 7;                                                \
            GLDS16(Kp + (size_t)(j0s + row) * 64 + (sl ^ (row & 7)) * 8, &Ks[P][c * 8]);  \
            GLDS16(Vp + (size_t)row * TT + j0s + (sl ^ ((row >> 1) & 7)) * 8,             \
                   &Vs[P][c * 8]);                                                        \
        }                                                                                 \
    }

    STAGE(0, 0);
    __syncthreads();

    const int ksw = l16 & 7;                  // K fragment slot swizzle
    const int vsw = (l16 >> 1) & 7;           // V fragment slot swizzle
    const int vsub = ((quad & 1) ^ (l16 & 1)) * 4;   // physical 8B half (vtrans-swapped)

    for (int it = 0; it < ntiles; ++it) {
        const int p = it & 1;
        if (it + 1 < ntiles) STAGE(it + 1, p ^ 1);

        // S^T = K Q^T: A = K rows (m = t = nt*16+l16), B = aq
        floatx4 sacc[4];
#pragma unroll
        for (int nt = 0; nt < 4; nt++) sacc[nt] = (floatx4){0.f, 0.f, 0.f, 0.f};
#pragma unroll
        for (int ks = 0; ks < 2; ks++)
#pragma unroll
            for (int nt = 0; nt < 4; nt++) {
                short8 kf = *(const short8*)&Ks[p][(nt * 16 + l16) * 64 + ((ks * 4 + quad) ^ ksw) * 8];
                sacc[nt] = __builtin_amdgcn_mfma_f32_16x16x32_bf16(kf, aq[ks], sacc[nt], 0, 0, 0);
            }

        // causal mask (diagonal tile only): t-local = nt*16+quad*4+r, q-local = w*16+l16
        if (it == qtile) {
            const int qg = w * 16 + l16;
#pragma unroll
            for (int nt = 0; nt < 4; nt++)
#pragma unroll
                for (int r = 0; r < 4; r++)
                    if (nt * 16 + quad * 4 + r > qg) sacc[nt][r] = -1e30f;
        }

        // online softmax, per-lane scalar state (q = l16), exp2 domain
        float mx = sacc[0][0];
#pragma unroll
        for (int nt = 0; nt < 4; nt++)
#pragma unroll
            for (int r = 0; r < 4; r++) mx = fmaxf(mx, sacc[nt][r]);
        mx = fmaxf(mx, __shfl_xor(mx, 16));
        mx = fmaxf(mx, __shfl_xor(mx, 32));
        float mnew  = fmaxf(m, mx);
        float alpha = __builtin_amdgcn_exp2f(m - mnew);
        m = mnew;
        float psum = 0.f;
#pragma unroll
        for (int nt = 0; nt < 4; nt++)
#pragma unroll
            for (int r = 0; r < 4; r++) {
                float pv = __builtin_amdgcn_exp2f(sacc[nt][r] - mnew);
                sacc[nt][r] = pv;
                psum += pv;
            }
        psum += __shfl_xor(psum, 16);
        psum += __shfl_xor(psum, 32);
        l = l * alpha + psum;

#pragma unroll
        for (int dt = 0; dt < 4; dt++)
#pragma unroll
            for (int r = 0; r < 4; r++) Oacc[dt][r] *= alpha;

        // P^T pack: C-layout == B-operand of 16x16x16 f16 (k = quad*4+j, n = l16)
        half4 bp[4];
#pragma unroll
        for (int nt = 0; nt < 4; nt++) {
            half4 h;
            h[0] = (_Float16)sacc[nt][0];
            h[1] = (_Float16)sacc[nt][1];
            h[2] = (_Float16)sacc[nt][2];
            h[3] = (_Float16)sacc[nt][3];
            bp[nt] = h;
        }

        // O^T += V^T · P^T   (A = V^T: m = d = dt*16+l16, k = nt*16 + quad*4 + j)
#pragma unroll
        for (int dt = 0; dt < 4; dt++)
#pragma unroll
            for (int nt = 0; nt < 4; nt++) {
                int c = nt * 2 + (quad >> 1);           // 16B chunk holding the 8B we need
                half4 vf = *(const half4*)&Vs[p][(dt * 16 + l16) * 64 + (c ^ vsw) * 8 + vsub];
                Oacc[dt] = MFMA_PV(vf, bp[nt], Oacc[dt]);
            }

        __syncthreads();   // drains stage(it+1); protects buffers for next iteration
    }
#undef STAGE

    // epilogue: out[b][t = q0 + w*16 + l16][h*64 + dt*16 + quad*4 + r] bf16
    const int b = bh >> 4, h = bh & 15;
    const float inv = 1.f / l;
    const size_t base = ((size_t)(b * TT + q0 + w * 16 + l16)) * DMODEL + h * 64 + quad * 4;
#pragma unroll
    for (int dt = 0; dt < 4; dt++) {
        ushort4 pk;
        pk.x = f2bf(Oacc[dt][0] * inv);
        pk.y = f2bf(Oacc[dt][1] * inv);
        pk.z = f2bf(Oacc[dt][2] * inv);
        pk.w = f2bf(Oacc[dt][3] * inv);
        *(ushort4*)(out + base + dt * 16) = pk;
    }
}

// ---------- launch ----------
extern "C" void kernel_launch(void* const* d_in, const int* in_sizes, int n_in,
                              void* d_out, int out_size, void* d_ws, size_t ws_size,
                              hipStream_t stream) {
    const float* x     = (const float*)d_in[0];   // [2,2048,1024]
    const float* w_qkv = (const float*)d_in[1];   // [3072,1024]
    const float* w_out = (const float*)d_in[2];   // [1024,1024]
    float* out = (float*)d_out;                   // [2,2048,1024]

    char* ws = (char*)d_ws;

    unsigned short* xb   = (unsigned short*)(ws);                 // 8 MB
    unsigned short* wqb  = (unsigned short*)(ws + 8388608);       // 6 MB
    unsigned short* wob  = (unsigned short*)(ws + 14680064);      // 2 MB
    float*          qkv  = (float*)(ws + 16777216);               // 48 MB
    unsigned short* qb   = (unsigned short*)(ws + 67108864);      // 8 MB
    unsigned short* kb   = (unsigned short*)(ws + 75497472);      // 8 MB
    unsigned short* vtb  = (unsigned short*)(ws + 83886080);      // 8 MB (f16)
    unsigned short* attb = (unsigned short*)(ws + 92274688);      // 8 MB

    castk3<<<8192, 256, 0, stream>>>(x, xb, w_qkv, wqb, w_out, wob);

    // qkv = x @ w_qkv^T   (M=4096, N=3072, K=1024)
    gemm_bt<<<dim3(3072 / 128, 4096 / 128), 256, 0, stream>>>(xb, wqb, qkv, 4096, 3072, 1024);

    rope_split<<<(BB * TT * NHEADS * 32) / 256, 256, 0, stream>>>(qkv, qb, kb);
    vtrans<<<dim3(TT / 64, BB * NHEADS), 256, 0, stream>>>(qkv, vtb);

    // grid: x = bh (XCD locality), y = qtile (reversed in kernel: longest first)
    attn_mfma<<<dim3(BB * NHEADS, TT / 64), 256, 0, stream>>>(qb, kb, vtb, attb);

    // out = attn @ w_out^T (M=4096, N=1024, K=1024)
    gemm_bt<<<dim3(1024 / 128, 4096 / 128), 256, 0, stream>>>(attb, wob, out, 4096, 1024, 1024);
}

// Round 11
// 195.770 us; speedup vs baseline: 1.7545x; 1.0281x over previous
//
#include <hip/hip_runtime.h>
#include <cstdint>
#include <cstddef>

// Problem constants
#define BB 2
#define TT 2048
#define DMODEL 1024
#define NHEADS 16
#define DK 64

typedef short short8 __attribute__((ext_vector_type(8)));
typedef unsigned short ushort8 __attribute__((ext_vector_type(8)));
typedef float floatx4 __attribute__((ext_vector_type(4)));
typedef _Float16 half4 __attribute__((ext_vector_type(4)));

// gfx950 f16 MFMA 16x16x16: A/B = 4xf16 (2 VGPR), C/D = 4xf32
#define MFMA_PV(A, B, C) __builtin_amdgcn_mfma_f32_16x16x16f16(A, B, C, 0, 0, 0)

// ---------- helpers ----------
__device__ __forceinline__ unsigned short f2bf(float f) {
    uint32_t u = __builtin_bit_cast(uint32_t, f);
    uint32_t r = (u + 0x7FFFu + ((u >> 16) & 1u)) >> 16;
    return (unsigned short)r;
}

#define GLDS16(g, l) __builtin_amdgcn_global_load_lds( \
    (const __attribute__((address_space(1))) void*)(g), \
    (__attribute__((address_space(3))) void*)(l), 16, 0, 0)

// ---------- merged cast fp32 -> bf16 for x, w_qkv, w_out (one launch) ----------
__global__ void castk3(const float* __restrict__ x, unsigned short* __restrict__ xb,
                       const float* __restrict__ wq, unsigned short* __restrict__ wqb,
                       const float* __restrict__ wo, unsigned short* __restrict__ wob) {
    int bid = blockIdx.x;
    const float* in;
    unsigned short* out;
    int base;
    if (bid < 4096)       { in = x;  out = xb;  base = bid * 1024; }
    else if (bid < 7168)  { in = wq; out = wqb; base = (bid - 4096) * 1024; }
    else                  { in = wo; out = wob; base = (bid - 7168) * 1024; }
    int i = base + threadIdx.x * 4;
    float4 v = *(const float4*)(in + i);
    ushort4 o;
    o.x = f2bf(v.x); o.y = f2bf(v.y); o.z = f2bf(v.z); o.w = f2bf(v.w);
    *(ushort4*)(out + i) = o;
}

// ---------- bf16 MFMA GEMM, C = A * B^T, BK=64 ----------
// A: [M][K], B: [N][K], C fp32 [M][N]. 128x128 tile, 16 k-iterations at K=1024
// (half the barrier drains of BK=32). Staging: 8 16B-chunks/row, slot = chunk ^ (row&7)
// -> b128 fragment reads cover all 32 banks per 8-lane phase (0 conflicts, R9/R10).
__global__ __launch_bounds__(256)
void gemm_bt(const unsigned short* __restrict__ A, const unsigned short* __restrict__ B,
             float* __restrict__ C, int M, int N, int K) {
    __shared__ unsigned short As[128 * 64];   // 16 KB
    __shared__ unsigned short Bs[128 * 64];   // 16 KB

    const int tid  = threadIdx.x;
    const int lane = tid & 63;
    const int w    = tid >> 6;
    const int wm   = w & 1;
    const int wn   = w >> 1;
    const int quad = lane >> 4;
    const int l16  = lane & 15;

    const int m0 = blockIdx.y * 128;
    const int n0 = blockIdx.x * 128;

    floatx4 acc[4][4];
#pragma unroll
    for (int a = 0; a < 4; a++)
#pragma unroll
        for (int b = 0; b < 4; b++)
            acc[a][b] = (floatx4){0.f, 0.f, 0.f, 0.f};

    // staging: 1024 chunks of 16B per tile, 4 per thread
    int srow[4], scol[4];
#pragma unroll
    for (int rep = 0; rep < 4; rep++) {
        int c = rep * 256 + tid;
        srow[rep] = c >> 3;
        scol[rep] = ((c & 7) ^ (srow[rep] & 7)) * 8;
    }

    const int fsw = l16 & 7;   // fragment slot swizzle key (row&7 == l16&7)

    for (int k0 = 0; k0 < K; k0 += 64) {
        __syncthreads();
#pragma unroll
        for (int rep = 0; rep < 4; rep++) {
            int c = rep * 256 + tid;
            GLDS16(A + (size_t)(m0 + srow[rep]) * K + k0 + scol[rep], &As[c * 8]);
            GLDS16(B + (size_t)(n0 + srow[rep]) * K + k0 + scol[rep], &Bs[c * 8]);
        }
        __syncthreads();

        short8 af[2][4], bf[2][4];
#pragma unroll
        for (int ks = 0; ks < 2; ks++)
#pragma unroll
            for (int t = 0; t < 4; t++) {
                af[ks][t] = *(const short8*)&As[(wm * 64 + t * 16 + l16) * 64 + ((ks * 4 + quad) ^ fsw) * 8];
                bf[ks][t] = *(const short8*)&Bs[(wn * 64 + t * 16 + l16) * 64 + ((ks * 4 + quad) ^ fsw) * 8];
            }
#pragma unroll
        for (int ks = 0; ks < 2; ks++)
#pragma unroll
            for (int tm = 0; tm < 4; tm++)
#pragma unroll
                for (int tn = 0; tn < 4; tn++)
                    acc[tm][tn] = __builtin_amdgcn_mfma_f32_16x16x32_bf16(
                        af[ks][tm], bf[ks][tn], acc[tm][tn], 0, 0, 0);
    }

#pragma unroll
    for (int tm = 0; tm < 4; tm++) {
#pragma unroll
        for (int tn = 0; tn < 4; tn++) {
#pragma unroll
            for (int r = 0; r < 4; r++) {
                int m = m0 + wm * 64 + tm * 16 + quad * 4 + r;
                int n = n0 + wn * 64 + tn * 16 + l16;
                C[(size_t)m * N + n] = acc[tm][tn][r];
            }
        }
    }
}

// ---------- fused RoPE split + V transpose (one launch, one pass) ----------
// Block: 64 t-rows of one head. Part 1: rope q,k -> qb,kb bf16 [B*H][T][64]
// (q pre-scaled by 0.125*log2(e)). Part 2: v -> vtb f16 [B*H][64][T] with the
// odd-row 8B half-swap (kills attn's phase-local V bank conflicts).
__global__ __launch_bounds__(256)
void ropevt(const float* __restrict__ qkv,
            unsigned short* __restrict__ qb, unsigned short* __restrict__ kb,
            unsigned short* __restrict__ vtb) {
    __shared__ float tile[64][65];
    const int tid = threadIdx.x;
    const int bh  = blockIdx.y;
    const int b = bh >> 4, h = bh & 15;
    const int t0 = blockIdx.x * 64;

    // ---- RoPE for q,k: 64 rows x 32 pairs = 2048 pairs, 8 per thread ----
    const float QS = 0.18033688f;   // 0.125 * log2(e)
#pragma unroll
    for (int rep = 0; rep < 8; rep++) {
        int idx  = rep * 256 + tid;
        int p    = idx & 31;
        int trow = idx >> 5;
        int t    = t0 + trow;

        size_t src = (size_t)(b * TT + t) * 3072 + h * 64 + 2 * p;
        float2 q = *(const float2*)(qkv + src);
        float2 k = *(const float2*)(qkv + src + 1024);

        float invf = __powf(10000.f, -((float)(2 * p)) / 64.f);
        float ang  = (float)t * invf;
        float sn, cs;
        __sincosf(ang, &sn, &cs);

        size_t dst = ((size_t)bh * TT + t) * 64 + 2 * p;
        ushort2 qo, ko;
        qo.x = f2bf((q.x * cs - q.y * sn) * QS); qo.y = f2bf((q.y * cs + q.x * sn) * QS);
        ko.x = f2bf(k.x * cs - k.y * sn); ko.y = f2bf(k.y * cs + k.x * sn);
        *(ushort2*)(qb + dst) = qo;
        *(ushort2*)(kb + dst) = ko;
    }

    // ---- V transpose ----
    const int row = tid >> 2;
    const float* src = qkv + ((size_t)(b * TT) + t0 + row) * 3072 + 2048 + h * 64;
#pragma unroll
    for (int i = 0; i < 4; i++) {
        int c4 = (tid & 3) * 4 + i;   // 0..15
        float4 v = *(const float4*)(src + c4 * 4);
        tile[row][c4 * 4 + 0] = v.x;
        tile[row][c4 * 4 + 1] = v.y;
        tile[row][c4 * 4 + 2] = v.z;
        tile[row][c4 * 4 + 3] = v.w;
    }
    __syncthreads();

    const int d  = tid >> 2;
    const int tc = tid & 3;
    const int hs = (d & 1) * 4;       // half-swap for odd rows
    ushort8 o0, o1;
#pragma unroll
    for (int i = 0; i < 8; i++) {
        _Float16 hv = (_Float16)tile[tc * 16 + (i ^ hs)][d];
        o0[i] = __builtin_bit_cast(unsigned short, hv);
    }
#pragma unroll
    for (int i = 0; i < 8; i++) {
        _Float16 hv = (_Float16)tile[tc * 16 + 8 + (i ^ hs)][d];
        o1[i] = __builtin_bit_cast(unsigned short, hv);
    }
    unsigned short* dst = vtb + ((size_t)bh * 64 + d) * TT + t0 + tc * 16;
    *(ushort8*)(dst) = o0;
    *(ushort8*)(dst + 8) = o1;
}

// ---------- MFMA flash attention (causal): transposed-S + double-buffered LDS ----------
__global__ __launch_bounds__(256, 5)
void attn_mfma(const unsigned short* __restrict__ qb,
               const unsigned short* __restrict__ kb,
               const unsigned short* __restrict__ vtb,
               unsigned short* __restrict__ out) {
    __shared__ unsigned short Ks[2][64 * 64];   // [t][d] bf16, chunk-swizzled
    __shared__ unsigned short Vs[2][64 * 64];   // [d][t] f16,  chunk-swizzled + half-swapped

    const int tid  = threadIdx.x;
    const int lane = tid & 63;
    const int w    = tid >> 6;
    const int quad = lane >> 4;
    const int l16  = lane & 15;

    const int bh    = blockIdx.x;                    // head pinned to one XCD (32 % 8)
    const int qtile = gridDim.y - 1 - blockIdx.y;    // longest first
    const int q0    = qtile * 64;

    const unsigned short* Qp = qb + ((size_t)bh * TT + q0 + w * 16) * 64;
    const unsigned short* Kp = kb + (size_t)bh * TT * 64;
    const unsigned short* Vp = vtb + (size_t)bh * 64 * TT;   // f16 bits in ushort

    short8 aq[2];
#pragma unroll
    for (int ks = 0; ks < 2; ks++)
        aq[ks] = *(const short8*)(Qp + (size_t)l16 * 64 + ks * 32 + quad * 8);

    floatx4 Oacc[4];   // O^T: row d = dt*16 + quad*4 + r, col q = l16
#pragma unroll
    for (int dt = 0; dt < 4; dt++) Oacc[dt] = (floatx4){0.f, 0.f, 0.f, 0.f};
    float m = -1e30f, l = 0.f;

    const int ntiles = qtile + 1;

#define STAGE(IT, P)                                                                      \
    {                                                                                     \
        const int j0s = (IT) * 64;                                                        \
        _Pragma("unroll")                                                                 \
        for (int rep = 0; rep < 2; rep++) {                                               \
            int c    = rep * 256 + tid;                                                   \
            int row  = c >> 3, sl = c & 7;                                                \
            GLDS16(Kp + (size_t)(j0s + row) * 64 + (sl ^ (row & 7)) * 8, &Ks[P][c * 8]);  \
            GLDS16(Vp + (size_t)row * TT + j0s + (sl ^ ((row >> 1) & 7)) * 8,             \
                   &Vs[P][c * 8]);                                                        \
        }                                                                                 \
    }

    STAGE(0, 0);
    __syncthreads();

    const int ksw = l16 & 7;
    const int vsw = (l16 >> 1) & 7;
    const int vsub = ((quad & 1) ^ (l16 & 1)) * 4;

    for (int it = 0; it < ntiles; ++it) {
        const int p = it & 1;
        if (it + 1 < ntiles) STAGE(it + 1, p ^ 1);

        floatx4 sacc[4];
#pragma unroll
        for (int nt = 0; nt < 4; nt++) sacc[nt] = (floatx4){0.f, 0.f, 0.f, 0.f};
#pragma unroll
        for (int ks = 0; ks < 2; ks++)
#pragma unroll
            for (int nt = 0; nt < 4; nt++) {
                short8 kf = *(const short8*)&Ks[p][(nt * 16 + l16) * 64 + ((ks * 4 + quad) ^ ksw) * 8];
                sacc[nt] = __builtin_amdgcn_mfma_f32_16x16x32_bf16(kf, aq[ks], sacc[nt], 0, 0, 0);
            }

        if (it == qtile) {
            const int qg = w * 16 + l16;
#pragma unroll
            for (int nt = 0; nt < 4; nt++)
#pragma unroll
                for (int r = 0; r < 4; r++)
                    if (nt * 16 + quad * 4 + r > qg) sacc[nt][r] = -1e30f;
        }

        float mx = sacc[0][0];
#pragma unroll
        for (int nt = 0; nt < 4; nt++)
#pragma unroll
            for (int r = 0; r < 4; r++) mx = fmaxf(mx, sacc[nt][r]);
        mx = fmaxf(mx, __shfl_xor(mx, 16));
        mx = fmaxf(mx, __shfl_xor(mx, 32));
        float mnew  = fmaxf(m, mx);
        float alpha = __builtin_amdgcn_exp2f(m - mnew);
        m = mnew;
        float psum = 0.f;
#pragma unroll
        for (int nt = 0; nt < 4; nt++)
#pragma unroll
            for (int r = 0; r < 4; r++) {
                float pv = __builtin_amdgcn_exp2f(sacc[nt][r] - mnew);
                sacc[nt][r] = pv;
                psum += pv;
            }
        psum += __shfl_xor(psum, 16);
        psum += __shfl_xor(psum, 32);
        l = l * alpha + psum;

#pragma unroll
        for (int dt = 0; dt < 4; dt++)
#pragma unroll
            for (int r = 0; r < 4; r++) Oacc[dt][r] *= alpha;

        half4 bp[4];
#pragma unroll
        for (int nt = 0; nt < 4; nt++) {
            half4 h;
            h[0] = (_Float16)sacc[nt][0];
            h[1] = (_Float16)sacc[nt][1];
            h[2] = (_Float16)sacc[nt][2];
            h[3] = (_Float16)sacc[nt][3];
            bp[nt] = h;
        }

#pragma unroll
        for (int dt = 0; dt < 4; dt++)
#pragma unroll
            for (int nt = 0; nt < 4; nt++) {
                int c = nt * 2 + (quad >> 1);
                half4 vf = *(const half4*)&Vs[p][(dt * 16 + l16) * 64 + (c ^ vsw) * 8 + vsub];
                Oacc[dt] = MFMA_PV(vf, bp[nt], Oacc[dt]);
            }

        __syncthreads();
    }
#undef STAGE

    const int b = bh >> 4, h = bh & 15;
    const float inv = 1.f / l;
    const size_t base = ((size_t)(b * TT + q0 + w * 16 + l16)) * DMODEL + h * 64 + quad * 4;
#pragma unroll
    for (int dt = 0; dt < 4; dt++) {
        ushort4 pk;
        pk.x = f2bf(Oacc[dt][0] * inv);
        pk.y = f2bf(Oacc[dt][1] * inv);
        pk.z = f2bf(Oacc[dt][2] * inv);
        pk.w = f2bf(Oacc[dt][3] * inv);
        *(ushort4*)(out + base + dt * 16) = pk;
    }
}

// ---------- launch ----------
extern "C" void kernel_launch(void* const* d_in, const int* in_sizes, int n_in,
                              void* d_out, int out_size, void* d_ws, size_t ws_size,
                              hipStream_t stream) {
    const float* x     = (const float*)d_in[0];   // [2,2048,1024]
    const float* w_qkv = (const float*)d_in[1];   // [3072,1024]
    const float* w_out = (const float*)d_in[2];   // [1024,1024]
    float* out = (float*)d_out;                   // [2,2048,1024]

    char* ws = (char*)d_ws;

    unsigned short* xb   = (unsigned short*)(ws);                 // 8 MB
    unsigned short* wqb  = (unsigned short*)(ws + 8388608);       // 6 MB
    unsigned short* wob  = (unsigned short*)(ws + 14680064);      // 2 MB
    float*          qkv  = (float*)(ws + 16777216);               // 48 MB
    unsigned short* qb   = (unsigned short*)(ws + 67108864);      // 8 MB
    unsigned short* kb   = (unsigned short*)(ws + 75497472);      // 8 MB
    unsigned short* vtb  = (unsigned short*)(ws + 83886080);      // 8 MB (f16)
    unsigned short* attb = (unsigned short*)(ws + 92274688);      // 8 MB

    castk3<<<8192, 256, 0, stream>>>(x, xb, w_qkv, wqb, w_out, wob);

    // qkv = x @ w_qkv^T   (M=4096, N=3072, K=1024)
    gemm_bt<<<dim3(3072 / 128, 4096 / 128), 256, 0, stream>>>(xb, wqb, qkv, 4096, 3072, 1024);

    // fused rope + v-transpose
    ropevt<<<dim3(TT / 64, BB * NHEADS), 256, 0, stream>>>(qkv, qb, kb, vtb);

    // grid: x = bh (XCD locality), y = qtile (reversed in kernel: longest first)
    attn_mfma<<<dim3(BB * NHEADS, TT / 64), 256, 0, stream>>>(qb, kb, vtb, attb);

    // out = attn @ w_out^T (M=4096, N=1024, K=1024)
    gemm_bt<<<dim3(1024 / 128, 4096 / 128), 256, 0, stream>>>(attb, wob, out, 4096, 1024, 1024);
}

// Round 12
// 191.657 us; speedup vs baseline: 1.7922x; 1.0215x over previous
//
#include <hip/hip_runtime.h>
#include <cstdint>
#include <cstddef>

// Problem constants
#define BB 2
#define TT 2048
#define DMODEL 1024
#define NHEADS 16
#define DK 64

typedef short short8 __attribute__((ext_vector_type(8)));
typedef unsigned short ushort8 __attribute__((ext_vector_type(8)));
typedef float floatx4 __attribute__((ext_vector_type(4)));
typedef _Float16 half4 __attribute__((ext_vector_type(4)));

// gfx950 f16 MFMA 16x16x16: A/B = 4xf16 (2 VGPR), C/D = 4xf32
#define MFMA_PV(A, B, C) __builtin_amdgcn_mfma_f32_16x16x16f16(A, B, C, 0, 0, 0)

// ---------- helpers ----------
__device__ __forceinline__ unsigned short f2bf(float f) {
    uint32_t u = __builtin_bit_cast(uint32_t, f);
    uint32_t r = (u + 0x7FFFu + ((u >> 16) & 1u)) >> 16;
    return (unsigned short)r;
}
__device__ __forceinline__ float bf2f(unsigned short s) {
    uint32_t u = ((uint32_t)s) << 16;
    return __builtin_bit_cast(float, u);
}

#define GLDS16(g, l) __builtin_amdgcn_global_load_lds( \
    (const __attribute__((address_space(1))) void*)(g), \
    (__attribute__((address_space(3))) void*)(l), 16, 0, 0)

// ---------- merged cast fp32 -> bf16 for x, w_qkv, w_out (one launch) ----------
__global__ void castk3(const float* __restrict__ x, unsigned short* __restrict__ xb,
                       const float* __restrict__ wq, unsigned short* __restrict__ wqb,
                       const float* __restrict__ wo, unsigned short* __restrict__ wob) {
    int bid = blockIdx.x;
    const float* in;
    unsigned short* out;
    int base;
    if (bid < 4096)       { in = x;  out = xb;  base = bid * 1024; }
    else if (bid < 7168)  { in = wq; out = wqb; base = (bid - 4096) * 1024; }
    else                  { in = wo; out = wob; base = (bid - 7168) * 1024; }
    int i = base + threadIdx.x * 4;
    float4 v = *(const float4*)(in + i);
    ushort4 o;
    o.x = f2bf(v.x); o.y = f2bf(v.y); o.z = f2bf(v.z); o.w = f2bf(v.w);
    *(ushort4*)(out + i) = o;
}

// ---------- bf16 MFMA GEMM, C = A * B^T, BK=32 (R10-proven: 0 conflicts) ----------
// A: [M][K], B: [N][K]. OUT = float (fp32 C) or unsigned short (bf16 C).
template <typename OUT>
__global__ __launch_bounds__(256)
void gemm_bt(const unsigned short* __restrict__ A, const unsigned short* __restrict__ B,
             OUT* __restrict__ C, int M, int N, int K) {
    __shared__ unsigned short As[128 * 32];
    __shared__ unsigned short Bs[128 * 32];

    const int tid  = threadIdx.x;
    const int lane = tid & 63;
    const int w    = tid >> 6;
    const int wm   = w & 1;
    const int wn   = w >> 1;
    const int quad = lane >> 4;
    const int l16  = lane & 15;

    const int m0 = blockIdx.y * 128;
    const int n0 = blockIdx.x * 128;

    floatx4 acc[4][4];
#pragma unroll
    for (int a = 0; a < 4; a++)
#pragma unroll
        for (int b = 0; b < 4; b++)
            acc[a][b] = (floatx4){0.f, 0.f, 0.f, 0.f};

    const int c0 = w * 128 + lane;
    const int c1 = c0 + 64;
    const int r0 = c0 >> 2, cc0 = (c0 & 3) ^ ((r0 >> 1) & 3);
    const int r1 = c1 >> 2, cc1 = (c1 & 3) ^ ((r1 >> 1) & 3);

    const unsigned short* gA0 = A + (size_t)(m0 + r0) * K + cc0 * 8;
    const unsigned short* gA1 = A + (size_t)(m0 + r1) * K + cc1 * 8;
    const unsigned short* gB0 = B + (size_t)(n0 + r0) * K + cc0 * 8;
    const unsigned short* gB1 = B + (size_t)(n0 + r1) * K + cc1 * 8;

    unsigned short* lA0 = &As[(2 * w + 0) * 512];
    unsigned short* lA1 = &As[(2 * w + 1) * 512];
    unsigned short* lB0 = &Bs[(2 * w + 0) * 512];
    unsigned short* lB1 = &Bs[(2 * w + 1) * 512];

    const int rsw = (l16 >> 1) & 3;

    for (int k0 = 0; k0 < K; k0 += 32) {
        __syncthreads();
        GLDS16(gA0 + k0, lA0);
        GLDS16(gA1 + k0, lA1);
        GLDS16(gB0 + k0, lB0);
        GLDS16(gB1 + k0, lB1);
        __syncthreads();

        short8 af[4], bf[4];
#pragma unroll
        for (int t = 0; t < 4; t++) {
            af[t] = *(const short8*)&As[(wm * 64 + t * 16 + l16) * 32 + (quad ^ rsw) * 8];
            bf[t] = *(const short8*)&Bs[(wn * 64 + t * 16 + l16) * 32 + (quad ^ rsw) * 8];
        }
#pragma unroll
        for (int tm = 0; tm < 4; tm++)
#pragma unroll
            for (int tn = 0; tn < 4; tn++)
                acc[tm][tn] = __builtin_amdgcn_mfma_f32_16x16x32_bf16(
                    af[tm], bf[tn], acc[tm][tn], 0, 0, 0);
    }

#pragma unroll
    for (int tm = 0; tm < 4; tm++) {
#pragma unroll
        for (int tn = 0; tn < 4; tn++) {
#pragma unroll
            for (int r = 0; r < 4; r++) {
                int m = m0 + wm * 64 + tm * 16 + quad * 4 + r;
                int n = n0 + wn * 64 + tn * 16 + l16;
                if constexpr (sizeof(OUT) == 4)
                    C[(size_t)m * N + n] = acc[tm][tn][r];
                else
                    C[(size_t)m * N + n] = f2bf(acc[tm][tn][r]);
            }
        }
    }
}

// ---------- fused RoPE split + V transpose, bf16 qkv input ----------
// Block: 64 t-rows of one head. Part 1: rope q,k -> qb,kb bf16 [B*H][T][64]
// (q pre-scaled by 0.125*log2(e)). Part 2: v -> vtb f16 [B*H][64][T] with the
// odd-row 8B half-swap (kills attn's phase-local V bank conflicts).
__global__ __launch_bounds__(256)
void ropevt(const unsigned short* __restrict__ qkv,
            unsigned short* __restrict__ qb, unsigned short* __restrict__ kb,
            unsigned short* __restrict__ vtb) {
    __shared__ unsigned short tile[64][72];   // V slice, bf16
    const int tid = threadIdx.x;
    const int bh  = blockIdx.y;
    const int b = bh >> 4, h = bh & 15;
    const int t0 = blockIdx.x * 64;

    // ---- RoPE for q,k: 64 rows x 32 pairs = 2048 pairs, 8 per thread ----
    const float QS = 0.18033688f;   // 0.125 * log2(e)
#pragma unroll
    for (int rep = 0; rep < 8; rep++) {
        int idx  = rep * 256 + tid;
        int p    = idx & 31;
        int trow = idx >> 5;
        int t    = t0 + trow;

        size_t src = (size_t)(b * TT + t) * 3072 + h * 64 + 2 * p;
        ushort2 qu = *(const ushort2*)(qkv + src);
        ushort2 ku = *(const ushort2*)(qkv + src + 1024);
        float qx = bf2f(qu.x), qy = bf2f(qu.y);
        float kx = bf2f(ku.x), ky = bf2f(ku.y);

        float invf = __powf(10000.f, -((float)(2 * p)) / 64.f);
        float ang  = (float)t * invf;
        float sn, cs;
        __sincosf(ang, &sn, &cs);

        size_t dst = ((size_t)bh * TT + t) * 64 + 2 * p;
        ushort2 qo, ko;
        qo.x = f2bf((qx * cs - qy * sn) * QS); qo.y = f2bf((qy * cs + qx * sn) * QS);
        ko.x = f2bf(kx * cs - ky * sn); ko.y = f2bf(ky * cs + kx * sn);
        *(ushort2*)(qb + dst) = qo;
        *(ushort2*)(kb + dst) = ko;
    }

    // ---- V transpose (bf16 in, f16 out) ----
    const int row = tid >> 2;
    const unsigned short* src = qkv + ((size_t)(b * TT) + t0 + row) * 3072 + 2048 + h * 64;
    {
        int cb = (tid & 3) * 16;                        // 16 cols per thread
        ushort8 v0 = *(const ushort8*)(src + cb);
        ushort8 v1 = *(const ushort8*)(src + cb + 8);
#pragma unroll
        for (int i = 0; i < 8; i++) tile[row][cb + i] = v0[i];
#pragma unroll
        for (int i = 0; i < 8; i++) tile[row][cb + 8 + i] = v1[i];
    }
    __syncthreads();

    const int d  = tid >> 2;
    const int tc = tid & 3;
    const int hs = (d & 1) * 4;       // half-swap for odd rows
    ushort8 o0, o1;
#pragma unroll
    for (int i = 0; i < 8; i++) {
        _Float16 hv = (_Float16)bf2f(tile[tc * 16 + (i ^ hs)][d]);
        o0[i] = __builtin_bit_cast(unsigned short, hv);
    }
#pragma unroll
    for (int i = 0; i < 8; i++) {
        _Float16 hv = (_Float16)bf2f(tile[tc * 16 + 8 + (i ^ hs)][d]);
        o1[i] = __builtin_bit_cast(unsigned short, hv);
    }
    unsigned short* dst = vtb + ((size_t)bh * 64 + d) * TT + t0 + tc * 16;
    *(ushort8*)(dst) = o0;
    *(ushort8*)(dst + 8) = o1;
}

// ---------- MFMA flash attention (causal): transposed-S + double-buffered LDS ----------
__global__ __launch_bounds__(256, 5)
void attn_mfma(const unsigned short* __restrict__ qb,
               const unsigned short* __restrict__ kb,
               const unsigned short* __restrict__ vtb,
               unsigned short* __restrict__ out) {
    __shared__ unsigned short Ks[2][64 * 64];   // [t][d] bf16, chunk-swizzled
    __shared__ unsigned short Vs[2][64 * 64];   // [d][t] f16,  chunk-swizzled + half-swapped

    const int tid  = threadIdx.x;
    const int lane = tid & 63;
    const int w    = tid >> 6;
    const int quad = lane >> 4;
    const int l16  = lane & 15;

    const int bh    = blockIdx.x;                    // head pinned to one XCD (32 % 8)
    const int qtile = gridDim.y - 1 - blockIdx.y;    // longest first
    const int q0    = qtile * 64;

    const unsigned short* Qp = qb + ((size_t)bh * TT + q0 + w * 16) * 64;
    const unsigned short* Kp = kb + (size_t)bh * TT * 64;
    const unsigned short* Vp = vtb + (size_t)bh * 64 * TT;   // f16 bits in ushort

    short8 aq[2];
#pragma unroll
    for (int ks = 0; ks < 2; ks++)
        aq[ks] = *(const short8*)(Qp + (size_t)l16 * 64 + ks * 32 + quad * 8);

    floatx4 Oacc[4];   // O^T: row d = dt*16 + quad*4 + r, col q = l16
#pragma unroll
    for (int dt = 0; dt < 4; dt++) Oacc[dt] = (floatx4){0.f, 0.f, 0.f, 0.f};
    float m = -1e30f, l = 0.f;

    const int ntiles = qtile + 1;

#define STAGE(IT, P)                                                                      \
    {                                                                                     \
        const int j0s = (IT) * 64;                                                        \
        _Pragma("unroll")                                                                 \
        for (int rep = 0; rep < 2; rep++) {                                               \
            int c    = rep * 256 + tid;                                                   \
            int row  = c >> 3, sl = c & 7;                                                \
            GLDS16(Kp + (size_t)(j0s + row) * 64 + (sl ^ (row & 7)) * 8, &Ks[P][c * 8]);  \
            GLDS16(Vp + (size_t)row * TT + j0s + (sl ^ ((row >> 1) & 7)) * 8,             \
                   &Vs[P][c * 8]);                                                        \
        }                                                                                 \
    }

    STAGE(0, 0);
    __syncthreads();

    const int ksw = l16 & 7;
    const int vsw = (l16 >> 1) & 7;
    const int vsub = ((quad & 1) ^ (l16 & 1)) * 4;

    for (int it = 0; it < ntiles; ++it) {
        const int p = it & 1;
        if (it + 1 < ntiles) STAGE(it + 1, p ^ 1);

        floatx4 sacc[4];
#pragma unroll
        for (int nt = 0; nt < 4; nt++) sacc[nt] = (floatx4){0.f, 0.f, 0.f, 0.f};
#pragma unroll
        for (int ks = 0; ks < 2; ks++)
#pragma unroll
            for (int nt = 0; nt < 4; nt++) {
                short8 kf = *(const short8*)&Ks[p][(nt * 16 + l16) * 64 + ((ks * 4 + quad) ^ ksw) * 8];
                sacc[nt] = __builtin_amdgcn_mfma_f32_16x16x32_bf16(kf, aq[ks], sacc[nt], 0, 0, 0);
            }

        if (it == qtile) {
            const int qg = w * 16 + l16;
#pragma unroll
            for (int nt = 0; nt < 4; nt++)
#pragma unroll
                for (int r = 0; r < 4; r++)
                    if (nt * 16 + quad * 4 + r > qg) sacc[nt][r] = -1e30f;
        }

        float mx = sacc[0][0];
#pragma unroll
        for (int nt = 0; nt < 4; nt++)
#pragma unroll
            for (int r = 0; r < 4; r++) mx = fmaxf(mx, sacc[nt][r]);
        mx = fmaxf(mx, __shfl_xor(mx, 16));
        mx = fmaxf(mx, __shfl_xor(mx, 32));
        float mnew  = fmaxf(m, mx);
        float alpha = __builtin_amdgcn_exp2f(m - mnew);
        m = mnew;
        float psum = 0.f;
#pragma unroll
        for (int nt = 0; nt < 4; nt++)
#pragma unroll
            for (int r = 0; r < 4; r++) {
                float pv = __builtin_amdgcn_exp2f(sacc[nt][r] - mnew);
                sacc[nt][r] = pv;
                psum += pv;
            }
        psum += __shfl_xor(psum, 16);
        psum += __shfl_xor(psum, 32);
        l = l * alpha + psum;

#pragma unroll
        for (int dt = 0; dt < 4; dt++)
#pragma unroll
            for (int r = 0; r < 4; r++) Oacc[dt][r] *= alpha;

        half4 bp[4];
#pragma unroll
        for (int nt = 0; nt < 4; nt++) {
            half4 h;
            h[0] = (_Float16)sacc[nt][0];
            h[1] = (_Float16)sacc[nt][1];
            h[2] = (_Float16)sacc[nt][2];
            h[3] = (_Float16)sacc[nt][3];
            bp[nt] = h;
        }

#pragma unroll
        for (int dt = 0; dt < 4; dt++)
#pragma unroll
            for (int nt = 0; nt < 4; nt++) {
                int c = nt * 2 + (quad >> 1);
                half4 vf = *(const half4*)&Vs[p][(dt * 16 + l16) * 64 + (c ^ vsw) * 8 + vsub];
                Oacc[dt] = MFMA_PV(vf, bp[nt], Oacc[dt]);
            }

        __syncthreads();
    }
#undef STAGE

    const int b = bh >> 4, h = bh & 15;
    const float inv = 1.f / l;
    const size_t base = ((size_t)(b * TT + q0 + w * 16 + l16)) * DMODEL + h * 64 + quad * 4;
#pragma unroll
    for (int dt = 0; dt < 4; dt++) {
        ushort4 pk;
        pk.x = f2bf(Oacc[dt][0] * inv);
        pk.y = f2bf(Oacc[dt][1] * inv);
        pk.z = f2bf(Oacc[dt][2] * inv);
        pk.w = f2bf(Oacc[dt][3] * inv);
        *(ushort4*)(out + base + dt * 16) = pk;
    }
}

// ---------- launch ----------
extern "C" void kernel_launch(void* const* d_in, const int* in_sizes, int n_in,
                              void* d_out, int out_size, void* d_ws, size_t ws_size,
                              hipStream_t stream) {
    const float* x     = (const float*)d_in[0];   // [2,2048,1024]
    const float* w_qkv = (const float*)d_in[1];   // [3072,1024]
    const float* w_out = (const float*)d_in[2];   // [1024,1024]
    float* out = (float*)d_out;                   // [2,2048,1024]

    char* ws = (char*)d_ws;

    unsigned short* xb   = (unsigned short*)(ws);                 // 8 MB
    unsigned short* wqb  = (unsigned short*)(ws + 8388608);       // 6 MB
    unsigned short* wob  = (unsigned short*)(ws + 14680064);      // 2 MB
    unsigned short* qkvb = (unsigned short*)(ws + 16777216);      // 24 MB (bf16)
    unsigned short* qb   = (unsigned short*)(ws + 41943040);      // 8 MB
    unsigned short* kb   = (unsigned short*)(ws + 50331648);      // 8 MB
    unsigned short* vtb  = (unsigned short*)(ws + 58720256);      // 8 MB (f16)
    unsigned short* attb = (unsigned short*)(ws + 67108864);      // 8 MB

    castk3<<<8192, 256, 0, stream>>>(x, xb, w_qkv, wqb, w_out, wob);

    // qkv = x @ w_qkv^T   (M=4096, N=3072, K=1024), bf16 output
    gemm_bt<unsigned short><<<dim3(3072 / 128, 4096 / 128), 256, 0, stream>>>(
        xb, wqb, qkvb, 4096, 3072, 1024);

    // fused rope + v-transpose (bf16 input)
    ropevt<<<dim3(TT / 64, BB * NHEADS), 256, 0, stream>>>(qkvb, qb, kb, vtb);

    // grid: x = bh (XCD locality), y = qtile (reversed in kernel: longest first)
    attn_mfma<<<dim3(BB * NHEADS, TT / 64), 256, 0, stream>>>(qb, kb, vtb, attb);

    // out = attn @ w_out^T (M=4096, N=1024, K=1024), fp32 output
    gemm_bt<float><<<dim3(1024 / 128, 4096 / 128), 256, 0, stream>>>(
        attb, wob, out, 4096, 1024, 1024);
}